// Round 8
// baseline (135.810 us; speedup 1.0000x reference)
//
#include <hip/hip_runtime.h>

// AggregationLayer: out[s][d] = mean over edges e with segment_ids[e]==s of
// values[gather_idx[e]][d].  segment_ids sorted -> contiguous segment ranges.
//
// R8: R7 established seg_mean_bf16 ~33us at ~5.9 TB/s effective (bf16 table
// halved gather bytes; aggregate-byte bound).  This round: (1) fuse the
// convert and starts passes into ONE prep kernel (block-range split) to save
// a launch; (2) non-temporal stores for `out` + nt loads for starts so the
// output stream doesn't evict bf16-table lines from L2.

#define D 64

typedef float  f4v __attribute__((ext_vector_type(4)));

// ---- Pass 0 (fused): blocks [0, cvt_blocks) convert f32->bf16 (+zero row);
//                      blocks [cvt_blocks, cvt_blocks+st_blocks) compute starts.
__global__ __launch_bounds__(256) void prep_kernel(
    const float* __restrict__ src,
    unsigned short* __restrict__ dst,
    const int* __restrict__ segment_ids,
    int*       __restrict__ starts,
    int n, int n_padded,          // value elems; multiples of 8
    int n_edges, int n_seg,
    int cvt_blocks)
{
    if ((int)blockIdx.x < cvt_blocks) {
        // ---------- convert ----------
        const int i = (blockIdx.x * blockDim.x + threadIdx.x) * 8;
        if (i >= n_padded) return;
        float4 a = make_float4(0.f, 0.f, 0.f, 0.f);
        float4 b = make_float4(0.f, 0.f, 0.f, 0.f);
        if (i < n) {
            a = *(const float4*)(src + i);
            b = *(const float4*)(src + i + 4);
        }
        #define PACK_BF16(x, y) ({                                     \
            unsigned ux = __float_as_uint(x);                          \
            unsigned uy = __float_as_uint(y);                          \
            ux = (ux + 0x7FFFu + ((ux >> 16) & 1u)) >> 16;             \
            uy = (uy + 0x7FFFu + ((uy >> 16) & 1u)) >> 16;             \
            ux | (uy << 16); })
        uint4 o;
        o.x = PACK_BF16(a.x, a.y);
        o.y = PACK_BF16(a.z, a.w);
        o.z = PACK_BF16(b.x, b.y);
        o.w = PACK_BF16(b.z, b.w);
        #undef PACK_BF16
        *(uint4*)(dst + i) = o;
    } else {
        // ---------- starts ----------
        const int e       = (blockIdx.x - cvt_blocks) * blockDim.x + threadIdx.x;
        const bool active = (e < n_edges);
        const int ec      = active ? e : (n_edges - 1);
        const int s       = segment_ids[ec];
        const int lane    = threadIdx.x & 63;
        int sprev         = __shfl_up(s, 1, 64);
        if (lane == 0) sprev = (ec == 0) ? -1 : segment_ids[ec - 1];
        if (active) {
            for (int t = sprev + 1; t <= s; ++t) starts[t] = e;
            if (e == n_edges - 1) {
                for (int t = s + 1; t <= n_seg; ++t) starts[t] = n_edges;
            }
        }
    }
}

// ---- Pass 1: one wave per two segments, bf16 gather -----------------------
// vals16: [n_src+1][64] bf16; row n_src is all zeros (absorbs invalid slots).
__global__ __launch_bounds__(256) void seg_mean_bf16_kernel(
    const unsigned short* __restrict__ vals16,
    const int*   __restrict__ gather_idx,
    const int*   __restrict__ starts,
    float*       __restrict__ out,
    int n_seg, int n_src)
{
    const int wave = (blockIdx.x * blockDim.x + threadIdx.x) >> 6;
    const int lane = threadIdx.x & 63;
    const int s0 = wave << 1;
    if (s0 >= n_seg) return;
    const int s1 = s0 + 1;
    const bool has1 = (s1 < n_seg);

    const int sub = lane >> 4;    // edge slot within group of 4
    const int cg  = lane & 15;    // column quad (4 bf16 = 8 B per lane)

    const int st0 = __builtin_nontemporal_load(starts + s0);
    const int en0 = __builtin_nontemporal_load(starts + s0 + 1);
    const int st1 = en0;
    const int en1 = has1 ? __builtin_nontemporal_load(starts + s1 + 1) : en0;

    const uint2* __restrict__ rows = (const uint2*)vals16; // 16 uint2 per row

    float4 acc0 = make_float4(0.f, 0.f, 0.f, 0.f);
    float4 acc1 = make_float4(0.f, 0.f, 0.f, 0.f);

    int b0 = st0, b1 = st1;
    while (b0 < en0 || b1 < en1) {
        const int ea0 = b0 + 0  + sub, ea1 = b0 + 4  + sub;
        const int ea2 = b0 + 8  + sub, ea3 = b0 + 12 + sub;
        const int eb0 = b1 + 0  + sub, eb1 = b1 + 4  + sub;
        const int eb2 = b1 + 8  + sub, eb3 = b1 + 12 + sub;
        const bool ma0 = ea0 < en0, ma1 = ea1 < en0, ma2 = ea2 < en0, ma3 = ea3 < en0;
        const bool mb0 = eb0 < en1, mb1 = eb1 < en1, mb2 = eb2 < en1, mb3 = eb3 < en1;
        // invalid slots -> zero row n_src (no masking needed downstream)
        const int ia0 = ma0 ? gather_idx[ea0] : n_src;
        const int ia1 = ma1 ? gather_idx[ea1] : n_src;
        const int ia2 = ma2 ? gather_idx[ea2] : n_src;
        const int ia3 = ma3 ? gather_idx[ea3] : n_src;
        const int ib0 = mb0 ? gather_idx[eb0] : n_src;
        const int ib1 = mb1 ? gather_idx[eb1] : n_src;
        const int ib2 = mb2 ? gather_idx[eb2] : n_src;
        const int ib3 = mb3 ? gather_idx[eb3] : n_src;
        const uint2 va0 = rows[((long long)ia0 << 4) + cg];
        const uint2 va1 = rows[((long long)ia1 << 4) + cg];
        const uint2 va2 = rows[((long long)ia2 << 4) + cg];
        const uint2 va3 = rows[((long long)ia3 << 4) + cg];
        const uint2 vb0 = rows[((long long)ib0 << 4) + cg];
        const uint2 vb1 = rows[((long long)ib1 << 4) + cg];
        const uint2 vb2 = rows[((long long)ib2 << 4) + cg];
        const uint2 vb3 = rows[((long long)ib3 << 4) + cg];
        #define ACC(A, V)                                              \
            A.x += __uint_as_float((V).x << 16);                       \
            A.y += __uint_as_float((V).x & 0xFFFF0000u);               \
            A.z += __uint_as_float((V).y << 16);                       \
            A.w += __uint_as_float((V).y & 0xFFFF0000u);
        ACC(acc0, va0) ACC(acc0, va1) ACC(acc0, va2) ACC(acc0, va3)
        ACC(acc1, vb0) ACC(acc1, vb1) ACC(acc1, vb2) ACC(acc1, vb3)
        #undef ACC
        b0 += 16; b1 += 16;
    }

    // butterfly-reduce each segment across the 4 sub-groups (xor 16, xor 32)
    acc0.x += __shfl_xor(acc0.x, 16, 64); acc0.y += __shfl_xor(acc0.y, 16, 64);
    acc0.z += __shfl_xor(acc0.z, 16, 64); acc0.w += __shfl_xor(acc0.w, 16, 64);
    acc0.x += __shfl_xor(acc0.x, 32, 64); acc0.y += __shfl_xor(acc0.y, 32, 64);
    acc0.z += __shfl_xor(acc0.z, 32, 64); acc0.w += __shfl_xor(acc0.w, 32, 64);
    acc1.x += __shfl_xor(acc1.x, 16, 64); acc1.y += __shfl_xor(acc1.y, 16, 64);
    acc1.z += __shfl_xor(acc1.z, 16, 64); acc1.w += __shfl_xor(acc1.w, 16, 64);
    acc1.x += __shfl_xor(acc1.x, 32, 64); acc1.y += __shfl_xor(acc1.y, 32, 64);
    acc1.z += __shfl_xor(acc1.z, 32, 64); acc1.w += __shfl_xor(acc1.w, 32, 64);

    const int c0 = en0 - st0;
    const int c1 = en1 - st1;
    const float inv0 = (c0 > 0) ? (1.0f / (float)c0) : 1.0f;
    const float inv1 = (c1 > 0) ? (1.0f / (float)c1) : 1.0f;

    // sub==0 lanes store segment s0's row, sub==1 lanes store s1's row
    if (sub == 0 || (sub == 1 && has1)) {
        f4v r;
        if (sub == 0) {
            r.x = acc0.x * inv0; r.y = acc0.y * inv0;
            r.z = acc0.z * inv0; r.w = acc0.w * inv0;
        } else {
            r.x = acc1.x * inv1; r.y = acc1.y * inv1;
            r.z = acc1.z * inv1; r.w = acc1.w * inv1;
        }
        const int s = s0 + sub;
        // non-temporal: don't let the output stream evict bf16-table L2 lines
        __builtin_nontemporal_store(r, (f4v*)(out + ((long long)s << 6) + (cg << 2)));
    }
}

// ---- Fallback (ws too small): f32 binary-search kernel --------------------
__global__ __launch_bounds__(256) void seg_mean_bsearch_kernel(
    const float* __restrict__ values,
    const int*   __restrict__ gather_idx,
    const int*   __restrict__ segment_ids,
    float*       __restrict__ out,
    int n_edges, int n_seg)
{
    const int wave = (blockIdx.x * blockDim.x + threadIdx.x) >> 6;
    const int lane = threadIdx.x & 63;
    if (wave >= n_seg) return;
    const int s = wave;
    int lo = 0, hi = n_edges;
    while (lo < hi) { int mid = (lo + hi) >> 1; if (segment_ids[mid] < s) lo = mid + 1; else hi = mid; }
    const int start = lo;
    hi = n_edges;
    while (lo < hi) { int mid = (lo + hi) >> 1; if (segment_ids[mid] < s + 1) lo = mid + 1; else hi = mid; }
    const int end = lo;
    float sum = 0.0f;
    for (int e = start; e < end; ++e) sum += values[((long long)gather_idx[e] << 6) + lane];
    const int count = end - start;
    const float inv = (count > 0) ? (1.0f / (float)count) : 1.0f;
    out[((long long)s << 6) + lane] = sum * inv;
}

extern "C" void kernel_launch(void* const* d_in, const int* in_sizes, int n_in,
                              void* d_out, int out_size, void* d_ws, size_t ws_size,
                              hipStream_t stream) {
    const float* values      = (const float*)d_in[0];
    const int*   gather_idx  = (const int*)d_in[1];
    const int*   segment_ids = (const int*)d_in[2];
    float* out = (float*)d_out;

    const int n_values = in_sizes[0];          // n_src * 64
    const int n_edges  = in_sizes[1];
    const int n_seg    = out_size / D;
    const int n_src    = n_values / D;

    // ws layout: [bf16 table incl. zero row][starts]
    const int    n_padded    = n_values + D;   // one zero row
    const size_t table_bytes = (size_t)n_padded * sizeof(unsigned short);
    const size_t starts_off  = (table_bytes + 15) & ~(size_t)15;
    const size_t need        = starts_off + (size_t)(n_seg + 1) * sizeof(int);

    if (ws_size >= need) {
        unsigned short* vals16 = (unsigned short*)d_ws;
        int* starts = (int*)((char*)d_ws + starts_off);
        {
            const int threads    = 256;
            const int cvt_blocks = (n_padded / 8 + threads - 1) / threads;
            const int st_blocks  = (n_edges + threads - 1) / threads;
            prep_kernel<<<cvt_blocks + st_blocks, threads, 0, stream>>>(
                values, vals16, segment_ids, starts,
                n_values, n_padded, n_edges, n_seg, cvt_blocks);
        }
        {
            const int n_waves = (n_seg + 1) >> 1;        // two segments per wave
            const int threads = 256;                     // 4 waves/block
            const int blocks  = (n_waves * 64 + threads - 1) / threads;
            seg_mean_bf16_kernel<<<blocks, threads, 0, stream>>>(
                vals16, gather_idx, starts, out, n_seg, n_src);
        }
    } else {
        const int threads = 256;
        const int blocks  = (n_seg * 64 + threads - 1) / threads;
        seg_mean_bsearch_kernel<<<blocks, threads, 0, stream>>>(
            values, gather_idx, segment_ids, out, n_edges, n_seg);
    }
}